// Round 11
// baseline (527.494 us; speedup 1.0000x reference)
//
#include <hip/hip_runtime.h>
#include <hip/hip_bf16.h>

// Problem constants (B,S,D) = (8, 2048, 1024), fp32 in/out, causal mask = tril.
#define Bb 8
#define Ss 2048
#define Dd 1024

typedef short bf16x8 __attribute__((ext_vector_type(8)));
typedef float f32x4  __attribute__((ext_vector_type(4)));

__device__ __forceinline__ short f2bf(float f) {
  union { __hip_bfloat16 h; short s; } u;
  u.h = __float2bfloat16(f);
  return u.s;
}
__device__ __forceinline__ float bf2f(short s) {
  union { unsigned int u; float f; } v;
  v.u = ((unsigned int)(unsigned short)s) << 16;
  return v.f;
}

// bf16 LDS tile [128][64]: 8 16B-slots/row, slot XOR-swizzled by row&7. (0-conflict R2-R10)
__device__ __forceinline__ int swz(int row, int slot) {
  return row * 64 + (((slot ^ row) & 7) << 3);
}

__device__ __forceinline__ void gld16(const void* g, void* l) {
  __builtin_amdgcn_global_load_lds((const __attribute__((address_space(1))) void*)g,
                                   (__attribute__((address_space(3))) void*)l, 16, 0, 0);
}

// Stage [128][64] bf16 tile (256 threads, 4 units each).
__device__ __forceinline__ void stage_glds(const short* __restrict__ src, int ld,
                                           short* lds, int tid) {
  int w = tid >> 6;
#pragma unroll
  for (int it = 0; it < 4; ++it) {
    int u = it * 256 + tid;
    int r = u >> 3;
    int ssrc = (u ^ r) & 7;
    gld16(src + (size_t)r * ld + ssrc * 8, lds + (size_t)(it * 256 + w * 64) * 8);
  }
}

// 256-thread 128x128 K-step, both bf16: 8+8 ds_read_b128, 32 MFMA.
__device__ __forceinline__ void mfma_tile(const short* ldsA, const short* ldsB,
                                          f32x4 acc[4][4], int wm, int wn, int lr, int lk) {
#pragma unroll
  for (int c = 0; c < 2; ++c) {
    bf16x8 afr[4], bfr[4];
#pragma unroll
    for (int m = 0; m < 4; ++m)
      afr[m] = *(const bf16x8*)&ldsA[swz(wm * 64 + m * 16 + lr, c * 4 + lk)];
#pragma unroll
    for (int n = 0; n < 4; ++n)
      bfr[n] = *(const bf16x8*)&ldsB[swz(wn * 64 + n * 16 + lr, c * 4 + lk)];
#pragma unroll
    for (int m = 0; m < 4; ++m)
#pragma unroll
      for (int n = 0; n < 4; ++n)
        acc[m][n] = __builtin_amdgcn_mfma_f32_16x16x32_bf16(afr[m], bfr[n], acc[m][n], 0, 0, 0);
  }
}

// ---------------- W cast + transpose: Wt[n][k] = bf16(W[k][n]) ----------------
__global__ void wcast_kernel(const float* __restrict__ Wq, const float* __restrict__ Wk,
                             const float* __restrict__ Wv,
                             short* __restrict__ WtQ, short* __restrict__ WtK,
                             short* __restrict__ WtV) {
  int z = blockIdx.z;
  const float* W = (z == 0) ? Wq : (z == 1) ? Wk : Wv;
  short* Wt      = (z == 0) ? WtQ : (z == 1) ? WtK : WtV;
  __shared__ float tile[32][33];
  int r0 = blockIdx.y * 32, c0 = blockIdx.x * 32;
  int tx = threadIdx.x, ty = threadIdx.y;  // (32,8)
#pragma unroll
  for (int ii = 0; ii < 4; ++ii) {
    int r = ty * 4 + ii;
    tile[r][tx] = W[(size_t)(r0 + r) * Dd + c0 + tx];
  }
  __syncthreads();
#pragma unroll
  for (int ii = 0; ii < 4; ++ii) {
    int c = ty * 4 + ii;
    Wt[(size_t)(c0 + c) * Dd + r0 + tx] = f2bf(tile[tx][c]);
  }
}

// ---------------- projections: A fragments direct from L2, W in LDS -----------
// out = A(fp32) @ W^T(bf16) + bias. A-panel is L2-resident (XCD swizzle: the 8
// n-blocks of a panel are consecutive on one XCD), so A frags are per-lane
// global loads (2x16B per (m,c), 128B-contiguous per 4-lane group) + in-reg cvt.
// Only W staged in LDS (16 KB, proven swz) -> drain is 4 glds; occupancy
// VGPR-bound (~16 waves/CU at <=128 VGPR).
__launch_bounds__(256, 4)
__global__ void proj_kernel(const float* __restrict__ Q, const float* __restrict__ Kin,
                            const float* __restrict__ V,
                            const short* __restrict__ WtQ, const short* __restrict__ WtK,
                            const short* __restrict__ WtV,
                            const float* __restrict__ bq, const float* __restrict__ bk,
                            const float* __restrict__ bv,
                            short* __restrict__ qb, short* __restrict__ kb,
                            short* __restrict__ vT) {
  __shared__ short ldsB[128 * 64];   // bf16 W tile, 16 KB, swz
  int z = blockIdx.y;
  const float* A    = (z == 0) ? Q : (z == 1) ? Kin : V;
  const short* W    = (z == 0) ? WtQ : (z == 1) ? WtK : WtV;
  const float* bias = (z == 0) ? bq : (z == 1) ? bk : bv;

  // XCD-aware decode: xcd = m&7; n fastest within XCD (A-panel L2 reuse).
  int r = blockIdx.x;                // 0..1023
  int x = r & 7;
  int s = r >> 3;
  int nblk = s & 7;
  int mblk = x + 8 * (s >> 3);
  int m0 = mblk * 128;
  int n0 = nblk * 128;

  int tid = threadIdx.x;
  int lane = tid & 63, w = tid >> 6;
  int wm = w >> 1, wn = w & 1;
  int lr = lane & 15, lk = lane >> 4;

  const short* Wb = W + (size_t)n0 * Dd;
  // per-lane A row bases (4 m-frags)
  const float* Arow[4];
#pragma unroll
  for (int m = 0; m < 4; ++m)
    Arow[m] = A + (size_t)(m0 + wm * 64 + m * 16 + lr) * Dd + lk * 8;

  f32x4 acc[4][4] = {};

  stage_glds(Wb, Dd, ldsB, tid);
  __syncthreads();                       // W tile 0 ready (implicit vmcnt drain)

  for (int t = 0; t < 16; ++t) {
    int k0 = t * 64;
#pragma unroll
    for (int c = 0; c < 2; ++c) {
      bf16x8 afr[4], bfr[4];
#pragma unroll
      for (int m = 0; m < 4; ++m) {
        const float* g = Arow[m] + k0 + c * 32;
        f32x4 a0 = *(const f32x4*)g;
        f32x4 a1 = *(const f32x4*)(g + 4);
        bf16x8 h;
        h[0] = f2bf(a0[0]); h[1] = f2bf(a0[1]); h[2] = f2bf(a0[2]); h[3] = f2bf(a0[3]);
        h[4] = f2bf(a1[0]); h[5] = f2bf(a1[1]); h[6] = f2bf(a1[2]); h[7] = f2bf(a1[3]);
        afr[m] = h;
      }
#pragma unroll
      for (int n = 0; n < 4; ++n)
        bfr[n] = *(const bf16x8*)&ldsB[swz(wn * 64 + n * 16 + lr, c * 4 + lk)];
#pragma unroll
      for (int m = 0; m < 4; ++m)
#pragma unroll
        for (int n = 0; n < 4; ++n)
          acc[m][n] = __builtin_amdgcn_mfma_f32_16x16x32_bf16(afr[m], bfr[n], acc[m][n], 0, 0, 0);
    }
    if (t + 1 < 16) {
      __syncthreads();                   // all waves done reading W tile t
      stage_glds(Wb + (t + 1) * 64, Dd, ldsB, tid);
      __syncthreads();                   // W tile t+1 ready
    }
  }

  if (z < 2) {
    short* out = (z == 0) ? qb : kb;
#pragma unroll
    for (int m = 0; m < 4; ++m)
#pragma unroll
      for (int n = 0; n < 4; ++n) {
        int col = n0 + wn * 64 + n * 16 + lr;
        float bv_ = bias[col];
        int rbase = m0 + wm * 64 + m * 16 + lk * 4;
#pragma unroll
        for (int rr = 0; rr < 4; ++rr)
          out[(size_t)(rbase + rr) * Dd + col] = f2bf(acc[m][n][rr] + bv_);
      }
  } else {
    // vT[b][d][s] = v[b][s][d] + bias[d]
#pragma unroll
    for (int m = 0; m < 4; ++m)
#pragma unroll
      for (int n = 0; n < 4; ++n) {
        int col = n0 + wn * 64 + n * 16 + lr;         // d
        float bv_ = bias[col];
        int rbase = m0 + wm * 64 + m * 16 + lk * 4;   // global row in [B*S]
        int bidx = rbase / Ss;
        int s0 = rbase & (Ss - 1);
        short4 h;
        h.x = f2bf(acc[m][n][0] + bv_);
        h.y = f2bf(acc[m][n][1] + bv_);
        h.z = f2bf(acc[m][n][2] + bv_);
        h.w = f2bf(acc[m][n][3] + bv_);
        *(short4*)&vT[(size_t)bidx * Dd * Ss + (size_t)col * Ss + s0] = h;
      }
  }
}

// ---------------- causal block-sparse scores: SP = bf16(mask(q@k^T/32)) ------
// Grid: 1088 1-D. XCD = batch; triangular (i,j) decode (no dead blocks).
__launch_bounds__(256, 4)
__global__ void score_kernel(const short* __restrict__ qb, const short* __restrict__ kb,
                             short* __restrict__ SP) {
  int d = blockIdx.x;
  int b = d & 7;
  int sidx = d >> 3;
  int i = (int)((sqrtf(8.f * sidx + 1.f) - 1.f) * 0.5f);
  while ((i + 1) * (i + 2) / 2 <= sidx) ++i;
  while (i * (i + 1) / 2 > sidx) --i;
  int j = sidx - i * (i + 1) / 2;    // j <= i

  __shared__ short ldsA[128 * 64];
  __shared__ short ldsB[128 * 64];
  int tid = threadIdx.x;
  int lane = tid & 63, w = tid >> 6;
  int wm = w >> 1, wn = w & 1;
  int lr = lane & 15, lk = lane >> 4;

  const short* Abase = qb + (size_t)b * Ss * Dd + (size_t)i * 128 * Dd;
  const short* Bbase = kb + (size_t)b * Ss * Dd + (size_t)j * 128 * Dd;

  f32x4 acc[4][4] = {};
  for (int k0 = 0; k0 < Dd; k0 += 64) {
    __syncthreads();
    stage_glds(Abase + k0, Dd, ldsA, tid);
    stage_glds(Bbase + k0, Dd, ldsB, tid);
    __syncthreads();
    mfma_tile(ldsA, ldsB, acc, wm, wn, lr, lk);
  }

  short* srow = SP + (size_t)b * Ss * Ss;
#pragma unroll
  for (int m = 0; m < 4; ++m)
#pragma unroll
    for (int n = 0; n < 4; ++n) {
      int colg = j * 128 + wn * 64 + n * 16 + lr;
      int rbase = i * 128 + wm * 64 + m * 16 + lk * 4;
#pragma unroll
      for (int rr = 0; rr < 4; ++rr) {
        int rowg = rbase + rr;
        float sv = acc[m][n][rr] * 0.03125f;  // 1/sqrt(1024)
        if (colg > rowg) sv = -1e9f;
        srow[(size_t)rowg * Ss + colg] = f2bf(sv);
      }
    }
}

// ---------------- row softmax, in place over SP (bf16, vectorized) ------------
__global__ void softmax_kernel(short* __restrict__ SP) {
  int row = blockIdx.x;               // 0..B*S-1
  int b = row >> 11;
  int q = row & (Ss - 1);
  int L = ((q >> 7) + 1) << 7;        // stored row length (multiple of 128)
  short* srow = SP + (size_t)b * Ss * Ss + (size_t)q * Ss;
  int tid = threadIdx.x;
  int lane = tid & 63, w = tid >> 6;
  int c8 = tid * 8;
  bool act = c8 < L;

  float v[8];
  float mx = -3.0e38f;
  if (act) {
    bf16x8 hv = *(const bf16x8*)&srow[c8];
#pragma unroll
    for (int j2 = 0; j2 < 8; ++j2) {
      v[j2] = bf2f(hv[j2]);
      mx = fmaxf(mx, v[j2]);
    }
  }
  __shared__ float red[8];
#pragma unroll
  for (int off = 32; off; off >>= 1) mx = fmaxf(mx, __shfl_xor(mx, off));
  if (lane == 0) red[w] = mx;
  __syncthreads();
  mx = fmaxf(fmaxf(red[0], red[1]), fmaxf(red[2], red[3]));

  float sum = 0.f;
  if (act) {
#pragma unroll
    for (int j2 = 0; j2 < 8; ++j2) {
      v[j2] = __expf(v[j2] - mx);
      sum += v[j2];
    }
  }
#pragma unroll
  for (int off = 32; off; off >>= 1) sum += __shfl_xor(sum, off);
  if (lane == 0) red[4 + w] = sum;
  __syncthreads();
  sum = red[4] + red[5] + red[6] + red[7];
  float inv = 1.0f / sum;

  if (act) {
    bf16x8 ho;
#pragma unroll
    for (int j2 = 0; j2 < 8; ++j2) ho[j2] = f2bf(v[j2] * inv);
    *(bf16x8*)&srow[c8] = ho;
  }
}

// ---------------- causal block-sparse PV: out = P @ v (fp32 out) ----------------
// Grid: 1024 1-D. XCD = batch; dblk fastest (P-tile L2 reuse within XCD).
__launch_bounds__(256, 4)
__global__ void pv_kernel(const short* __restrict__ SP, const short* __restrict__ vT,
                          float* __restrict__ out) {
  int d = blockIdx.x;
  int b = d & 7;
  int s = d >> 3;
  int i = s >> 3;
  int dblk = s & 7;

  __shared__ short ldsA[128 * 64];
  __shared__ short ldsB[128 * 64];
  int tid = threadIdx.x;
  int lane = tid & 63, w = tid >> 6;
  int wm = w >> 1, wn = w & 1;
  int lr = lane & 15, lk = lane >> 4;

  const short* Abase = SP + (size_t)b * Ss * Ss + (size_t)i * 128 * Ss;
  const short* Bbase = vT + (size_t)b * Dd * Ss + (size_t)dblk * 128 * Ss;
  int KL = (i + 1) * 128;

  f32x4 acc[4][4] = {};
  for (int k0 = 0; k0 < KL; k0 += 64) {
    __syncthreads();
    stage_glds(Abase + k0, Ss, ldsA, tid);
    stage_glds(Bbase + k0, Ss, ldsB, tid);
    __syncthreads();
    mfma_tile(ldsA, ldsB, acc, wm, wn, lr, lk);
  }

#pragma unroll
  for (int m = 0; m < 4; ++m)
#pragma unroll
    for (int n = 0; n < 4; ++n) {
      int colg = dblk * 128 + wn * 64 + n * 16 + lr;
      int rbase = i * 128 + wm * 64 + m * 16 + lk * 4;
#pragma unroll
      for (int rr = 0; rr < 4; ++rr)
        out[(size_t)b * Ss * Dd + (size_t)(rbase + rr) * Dd + colg] = acc[m][n][rr];
    }
}

extern "C" void kernel_launch(void* const* d_in, const int* in_sizes, int n_in,
                              void* d_out, int out_size, void* d_ws, size_t ws_size,
                              hipStream_t stream) {
  const float* Q  = (const float*)d_in[0];
  const float* K  = (const float*)d_in[1];
  const float* V  = (const float*)d_in[2];
  const float* Wq = (const float*)d_in[3];
  const float* Wk = (const float*)d_in[4];
  const float* Wv = (const float*)d_in[5];
  const float* bq = (const float*)d_in[6];
  const float* bk = (const float*)d_in[7];
  const float* bv = (const float*)d_in[8];
  float* out = (float*)d_out;

  char* ws = (char*)d_ws;
  size_t off = 0;
  short* WtQ = (short*)(ws + off); off += (size_t)Dd * Dd * 2;
  short* WtK = (short*)(ws + off); off += (size_t)Dd * Dd * 2;
  short* WtV = (short*)(ws + off); off += (size_t)Dd * Dd * 2;
  short* qb  = (short*)(ws + off); off += (size_t)Bb * Ss * Dd * 2;
  short* kb  = (short*)(ws + off); off += (size_t)Bb * Ss * Dd * 2;
  short* vT  = (short*)(ws + off); off += (size_t)Bb * Ss * Dd * 2;
  short* SP  = (short*)(ws + off); off += (size_t)Bb * Ss * Ss * 2;  // scores/P in place
  (void)ws_size; (void)in_sizes; (void)n_in; (void)out_size;

  wcast_kernel<<<dim3(32, 32, 3), dim3(32, 8), 0, stream>>>(Wq, Wk, Wv, WtQ, WtK, WtV);
  proj_kernel<<<dim3(1024, 3), 256, 0, stream>>>(Q, K, V, WtQ, WtK, WtV, bq, bk, bv,
                                                 qb, kb, vT);
  score_kernel<<<dim3(1088), 256, 0, stream>>>(qb, kb, SP);
  softmax_kernel<<<dim3(Bb * Ss), 256, 0, stream>>>(SP);
  pv_kernel<<<dim3(1024), 256, 0, stream>>>(SP, vT, out);
}

// Round 12
// 286.343 us; speedup vs baseline: 1.8422x; 1.8422x over previous
//
#include <hip/hip_runtime.h>
#include <hip/hip_bf16.h>

// Problem constants (B,S,D) = (8, 2048, 1024), fp32 in/out, causal mask = tril.
#define Bb 8
#define Ss 2048
#define Dd 1024

typedef short bf16x8 __attribute__((ext_vector_type(8)));
typedef float f32x4  __attribute__((ext_vector_type(4)));

__device__ __forceinline__ short f2bf(float f) {
  union { __hip_bfloat16 h; short s; } u;
  u.h = __float2bfloat16(f);
  return u.s;
}
__device__ __forceinline__ float bf2f(short s) {
  union { unsigned int u; float f; } v;
  v.u = ((unsigned int)(unsigned short)s) << 16;
  return v.f;
}

// bf16 LDS tile [128][64]: 8 16B-slots/row, slot XOR-swizzled by row&7. (0-conflict R2-R10)
__device__ __forceinline__ int swz(int row, int slot) {
  return row * 64 + (((slot ^ row) & 7) << 3);
}
// fp32 LDS tile [128][64]: 16 16B-slots/row, XOR row&15. Float index. (0-conflict R5/R10)
__device__ __forceinline__ int swzf(int row, int slot) {
  return row * 64 + (((slot ^ row) & 15) << 2);
}

__device__ __forceinline__ void gld16(const void* g, void* l) {
  __builtin_amdgcn_global_load_lds((const __attribute__((address_space(1))) void*)g,
                                   (__attribute__((address_space(3))) void*)l, 16, 0, 0);
}

// Stage [128][64] bf16 tile (256 threads, 4 units each).
__device__ __forceinline__ void stage_glds(const short* __restrict__ src, int ld,
                                           short* lds, int tid) {
  int w = tid >> 6;
#pragma unroll
  for (int it = 0; it < 4; ++it) {
    int u = it * 256 + tid;
    int r = u >> 3;
    int ssrc = (u ^ r) & 7;
    gld16(src + (size_t)r * ld + ssrc * 8, lds + (size_t)(it * 256 + w * 64) * 8);
  }
}

// Stage [128][64] fp32 tile into swzf layout (256 threads, 8 units each). (0-conflict)
__device__ __forceinline__ void stage_glds_f32(const float* __restrict__ src, int ld,
                                               float* lds, int tid) {
  int w = tid >> 6;
#pragma unroll
  for (int it = 0; it < 8; ++it) {
    int u = it * 256 + tid;          // 16B-unit index, 0..2047
    int r = u >> 4;                  // row
    int ssrc = (u ^ r) & 15;         // pre-swizzled source slot (involution)
    gld16(src + (size_t)r * ld + ssrc * 4, lds + (size_t)(it * 256 + w * 64) * 4);
  }
}

// 256-thread 128x128 K-step, both bf16: 8+8 ds_read_b128, 32 MFMA.
__device__ __forceinline__ void mfma_tile(const short* ldsA, const short* ldsB,
                                          f32x4 acc[4][4], int wm, int wn, int lr, int lk) {
#pragma unroll
  for (int c = 0; c < 2; ++c) {
    bf16x8 afr[4], bfr[4];
#pragma unroll
    for (int m = 0; m < 4; ++m)
      afr[m] = *(const bf16x8*)&ldsA[swz(wm * 64 + m * 16 + lr, c * 4 + lk)];
#pragma unroll
    for (int n = 0; n < 4; ++n)
      bfr[n] = *(const bf16x8*)&ldsB[swz(wn * 64 + n * 16 + lr, c * 4 + lk)];
#pragma unroll
    for (int m = 0; m < 4; ++m)
#pragma unroll
      for (int n = 0; n < 4; ++n)
        acc[m][n] = __builtin_amdgcn_mfma_f32_16x16x32_bf16(afr[m], bfr[n], acc[m][n], 0, 0, 0);
  }
}

// K-step with A fp32 in LDS (cvt at read), B bf16. (R5/R10-proven, 0-conflict)
__device__ __forceinline__ void mfma_tile_f32A(const float* ldsA, const short* ldsB,
                                               f32x4 acc[4][4], int wm, int wn,
                                               int lr, int lk) {
#pragma unroll
  for (int c = 0; c < 2; ++c) {
    bf16x8 afr[4], bfr[4];
#pragma unroll
    for (int m = 0; m < 4; ++m) {
      int r = wm * 64 + m * 16 + lr;
      int s0 = c * 8 + lk * 2;
      f32x4 a0 = *(const f32x4*)&ldsA[swzf(r, s0)];
      f32x4 a1 = *(const f32x4*)&ldsA[swzf(r, s0 + 1)];
      bf16x8 h;
      h[0] = f2bf(a0[0]); h[1] = f2bf(a0[1]); h[2] = f2bf(a0[2]); h[3] = f2bf(a0[3]);
      h[4] = f2bf(a1[0]); h[5] = f2bf(a1[1]); h[6] = f2bf(a1[2]); h[7] = f2bf(a1[3]);
      afr[m] = h;
    }
#pragma unroll
    for (int n = 0; n < 4; ++n)
      bfr[n] = *(const bf16x8*)&ldsB[swz(wn * 64 + n * 16 + lr, c * 4 + lk)];
#pragma unroll
    for (int m = 0; m < 4; ++m)
#pragma unroll
      for (int n = 0; n < 4; ++n)
        acc[m][n] = __builtin_amdgcn_mfma_f32_16x16x32_bf16(afr[m], bfr[n], acc[m][n], 0, 0, 0);
  }
}

// ---------------- W cast + transpose: Wt[n][k] = bf16(W[k][n]) ----------------
__global__ void wcast_kernel(const float* __restrict__ Wq, const float* __restrict__ Wk,
                             const float* __restrict__ Wv,
                             short* __restrict__ WtQ, short* __restrict__ WtK,
                             short* __restrict__ WtV) {
  int z = blockIdx.z;
  const float* W = (z == 0) ? Wq : (z == 1) ? Wk : Wv;
  short* Wt      = (z == 0) ? WtQ : (z == 1) ? WtK : WtV;
  __shared__ float tile[32][33];
  int r0 = blockIdx.y * 32, c0 = blockIdx.x * 32;
  int tx = threadIdx.x, ty = threadIdx.y;  // (32,8)
#pragma unroll
  for (int ii = 0; ii < 4; ++ii) {
    int r = ty * 4 + ii;
    tile[r][tx] = W[(size_t)(r0 + r) * Dd + c0 + tx];
  }
  __syncthreads();
#pragma unroll
  for (int ii = 0; ii < 4; ++ii) {
    int c = ty * 4 + ii;
    Wt[(size_t)(c0 + c) * Dd + r0 + tx] = f2bf(tile[tx][c]);
  }
}

// ---------------- projections (R10-proven: 190 µs, 0 conflicts) ---------------
// out = A(fp32, staged direct via glds) @ W^T(bf16) + bias. BK=64, 48KB LDS,
// 3 blocks/CU. XCD decode: xcd = m&7, n fastest (A-panel L2 reuse).
__launch_bounds__(256, 3)
__global__ void proj_kernel(const float* __restrict__ Q, const float* __restrict__ Kin,
                            const float* __restrict__ V,
                            const short* __restrict__ WtQ, const short* __restrict__ WtK,
                            const short* __restrict__ WtV,
                            const float* __restrict__ bq, const float* __restrict__ bk,
                            const float* __restrict__ bv,
                            short* __restrict__ qb, short* __restrict__ kb,
                            short* __restrict__ vT) {
  __shared__ float ldsA[128 * 64];   // fp32 A tile, 32 KB, swzf
  __shared__ short ldsB[128 * 64];   // bf16 W tile, 16 KB, swz
  int z = blockIdx.y;
  const float* A    = (z == 0) ? Q : (z == 1) ? Kin : V;
  const short* W    = (z == 0) ? WtQ : (z == 1) ? WtK : WtV;
  const float* bias = (z == 0) ? bq : (z == 1) ? bk : bv;

  int r = blockIdx.x;                // 0..1023
  int x = r & 7;
  int s = r >> 3;
  int nblk = s & 7;
  int mblk = x + 8 * (s >> 3);
  int m0 = mblk * 128;
  int n0 = nblk * 128;

  int tid = threadIdx.x;
  int lane = tid & 63, w = tid >> 6;
  int wm = w >> 1, wn = w & 1;
  int lr = lane & 15, lk = lane >> 4;

  const float* Ab = A + (size_t)m0 * Dd;
  const short* Wb = W + (size_t)n0 * Dd;

  f32x4 acc[4][4] = {};
  for (int k0 = 0; k0 < Dd; k0 += 64) {
    __syncthreads();
    stage_glds_f32(Ab + k0, Dd, ldsA, tid);
    stage_glds(Wb + k0, Dd, ldsB, tid);
    __syncthreads();
    mfma_tile_f32A(ldsA, ldsB, acc, wm, wn, lr, lk);
  }

  if (z < 2) {
    short* out = (z == 0) ? qb : kb;
#pragma unroll
    for (int m = 0; m < 4; ++m)
#pragma unroll
      for (int n = 0; n < 4; ++n) {
        int col = n0 + wn * 64 + n * 16 + lr;
        float bv_ = bias[col];
        int rbase = m0 + wm * 64 + m * 16 + lk * 4;
#pragma unroll
        for (int rr = 0; rr < 4; ++rr)
          out[(size_t)(rbase + rr) * Dd + col] = f2bf(acc[m][n][rr] + bv_);
      }
  } else {
    // vT[b][d][s] = v[b][s][d] + bias[d]
#pragma unroll
    for (int m = 0; m < 4; ++m)
#pragma unroll
      for (int n = 0; n < 4; ++n) {
        int col = n0 + wn * 64 + n * 16 + lr;         // d
        float bv_ = bias[col];
        int rbase = m0 + wm * 64 + m * 16 + lk * 4;   // global row in [B*S]
        int bidx = rbase / Ss;
        int s0 = rbase & (Ss - 1);
        short4 h;
        h.x = f2bf(acc[m][n][0] + bv_);
        h.y = f2bf(acc[m][n][1] + bv_);
        h.z = f2bf(acc[m][n][2] + bv_);
        h.w = f2bf(acc[m][n][3] + bv_);
        *(short4*)&vT[(size_t)bidx * Dd * Ss + (size_t)col * Ss + s0] = h;
      }
  }
}

// ---------------- causal block-sparse scores: SP = bf16(mask(q@k^T/32)) ------
// Grid: 1088 1-D. XCD = batch; triangular (i,j) decode (no dead blocks).
__launch_bounds__(256, 4)
__global__ void score_kernel(const short* __restrict__ qb, const short* __restrict__ kb,
                             short* __restrict__ SP) {
  int d = blockIdx.x;
  int b = d & 7;
  int sidx = d >> 3;
  int i = (int)((sqrtf(8.f * sidx + 1.f) - 1.f) * 0.5f);
  while ((i + 1) * (i + 2) / 2 <= sidx) ++i;
  while (i * (i + 1) / 2 > sidx) --i;
  int j = sidx - i * (i + 1) / 2;    // j <= i

  __shared__ short ldsA[128 * 64];
  __shared__ short ldsB[128 * 64];
  int tid = threadIdx.x;
  int lane = tid & 63, w = tid >> 6;
  int wm = w >> 1, wn = w & 1;
  int lr = lane & 15, lk = lane >> 4;

  const short* Abase = qb + (size_t)b * Ss * Dd + (size_t)i * 128 * Dd;
  const short* Bbase = kb + (size_t)b * Ss * Dd + (size_t)j * 128 * Dd;

  f32x4 acc[4][4] = {};
  for (int k0 = 0; k0 < Dd; k0 += 64) {
    __syncthreads();
    stage_glds(Abase + k0, Dd, ldsA, tid);
    stage_glds(Bbase + k0, Dd, ldsB, tid);
    __syncthreads();
    mfma_tile(ldsA, ldsB, acc, wm, wn, lr, lk);
  }

  short* srow = SP + (size_t)b * Ss * Ss;
#pragma unroll
  for (int m = 0; m < 4; ++m)
#pragma unroll
    for (int n = 0; n < 4; ++n) {
      int colg = j * 128 + wn * 64 + n * 16 + lr;
      int rbase = i * 128 + wm * 64 + m * 16 + lk * 4;
#pragma unroll
      for (int rr = 0; rr < 4; ++rr) {
        int rowg = rbase + rr;
        float sv = acc[m][n][rr] * 0.03125f;  // 1/sqrt(1024)
        if (colg > rowg) sv = -1e9f;
        srow[(size_t)rowg * Ss + colg] = f2bf(sv);
      }
    }
}

// ---------------- row softmax, in place over SP (bf16, vectorized) ------------
__global__ void softmax_kernel(short* __restrict__ SP) {
  int row = blockIdx.x;               // 0..B*S-1
  int b = row >> 11;
  int q = row & (Ss - 1);
  int L = ((q >> 7) + 1) << 7;        // stored row length (multiple of 128)
  short* srow = SP + (size_t)b * Ss * Ss + (size_t)q * Ss;
  int tid = threadIdx.x;
  int lane = tid & 63, w = tid >> 6;
  int c8 = tid * 8;
  bool act = c8 < L;

  float v[8];
  float mx = -3.0e38f;
  if (act) {
    bf16x8 hv = *(const bf16x8*)&srow[c8];
#pragma unroll
    for (int j2 = 0; j2 < 8; ++j2) {
      v[j2] = bf2f(hv[j2]);
      mx = fmaxf(mx, v[j2]);
    }
  }
  __shared__ float red[8];
#pragma unroll
  for (int off = 32; off; off >>= 1) mx = fmaxf(mx, __shfl_xor(mx, off));
  if (lane == 0) red[w] = mx;
  __syncthreads();
  mx = fmaxf(fmaxf(red[0], red[1]), fmaxf(red[2], red[3]));

  float sum = 0.f;
  if (act) {
#pragma unroll
    for (int j2 = 0; j2 < 8; ++j2) {
      v[j2] = __expf(v[j2] - mx);
      sum += v[j2];
    }
  }
#pragma unroll
  for (int off = 32; off; off >>= 1) sum += __shfl_xor(sum, off);
  if (lane == 0) red[4 + w] = sum;
  __syncthreads();
  sum = red[4] + red[5] + red[6] + red[7];
  float inv = 1.0f / sum;

  if (act) {
    bf16x8 ho;
#pragma unroll
    for (int j2 = 0; j2 < 8; ++j2) ho[j2] = f2bf(v[j2] * inv);
    *(bf16x8*)&srow[c8] = ho;
  }
}

// ---------------- causal block-sparse PV: out = P @ v (fp32 out) ----------------
// Grid: 1024 1-D. XCD = batch; dblk fastest (P-tile L2 reuse within XCD).
__launch_bounds__(256, 4)
__global__ void pv_kernel(const short* __restrict__ SP, const short* __restrict__ vT,
                          float* __restrict__ out) {
  int d = blockIdx.x;
  int b = d & 7;
  int s = d >> 3;
  int i = s >> 3;
  int dblk = s & 7;

  __shared__ short ldsA[128 * 64];
  __shared__ short ldsB[128 * 64];
  int tid = threadIdx.x;
  int lane = tid & 63, w = tid >> 6;
  int wm = w >> 1, wn = w & 1;
  int lr = lane & 15, lk = lane >> 4;

  const short* Abase = SP + (size_t)b * Ss * Ss + (size_t)i * 128 * Ss;
  const short* Bbase = vT + (size_t)b * Dd * Ss + (size_t)dblk * 128 * Ss;
  int KL = (i + 1) * 128;

  f32x4 acc[4][4] = {};
  for (int k0 = 0; k0 < KL; k0 += 64) {
    __syncthreads();
    stage_glds(Abase + k0, Ss, ldsA, tid);
    stage_glds(Bbase + k0, Ss, ldsB, tid);
    __syncthreads();
    mfma_tile(ldsA, ldsB, acc, wm, wn, lr, lk);
  }

#pragma unroll
  for (int m = 0; m < 4; ++m)
#pragma unroll
    for (int n = 0; n < 4; ++n) {
      int colg = dblk * 128 + wn * 64 + n * 16 + lr;
      int rbase = i * 128 + wm * 64 + m * 16 + lk * 4;
#pragma unroll
      for (int rr = 0; rr < 4; ++rr)
        out[(size_t)b * Ss * Dd + (size_t)(rbase + rr) * Dd + colg] = acc[m][n][rr];
    }
}

extern "C" void kernel_launch(void* const* d_in, const int* in_sizes, int n_in,
                              void* d_out, int out_size, void* d_ws, size_t ws_size,
                              hipStream_t stream) {
  const float* Q  = (const float*)d_in[0];
  const float* K  = (const float*)d_in[1];
  const float* V  = (const float*)d_in[2];
  const float* Wq = (const float*)d_in[3];
  const float* Wk = (const float*)d_in[4];
  const float* Wv = (const float*)d_in[5];
  const float* bq = (const float*)d_in[6];
  const float* bk = (const float*)d_in[7];
  const float* bv = (const float*)d_in[8];
  float* out = (float*)d_out;

  char* ws = (char*)d_ws;
  size_t off = 0;
  short* WtQ = (short*)(ws + off); off += (size_t)Dd * Dd * 2;
  short* WtK = (short*)(ws + off); off += (size_t)Dd * Dd * 2;
  short* WtV = (short*)(ws + off); off += (size_t)Dd * Dd * 2;
  short* qb  = (short*)(ws + off); off += (size_t)Bb * Ss * Dd * 2;
  short* kb  = (short*)(ws + off); off += (size_t)Bb * Ss * Dd * 2;
  short* vT  = (short*)(ws + off); off += (size_t)Bb * Ss * Dd * 2;
  short* SP  = (short*)(ws + off); off += (size_t)Bb * Ss * Ss * 2;  // scores/P in place
  (void)ws_size; (void)in_sizes; (void)n_in; (void)out_size;

  wcast_kernel<<<dim3(32, 32, 3), dim3(32, 8), 0, stream>>>(Wq, Wk, Wv, WtQ, WtK, WtV);
  proj_kernel<<<dim3(1024, 3), 256, 0, stream>>>(Q, K, V, WtQ, WtK, WtV, bq, bk, bv,
                                                 qb, kb, vT);
  score_kernel<<<dim3(1088), 256, 0, stream>>>(qb, kb, SP);
  softmax_kernel<<<dim3(Bb * Ss), 256, 0, stream>>>(SP);
  pv_kernel<<<dim3(1024), 256, 0, stream>>>(SP, vT, out);
}